// Round 1
// baseline (3187.559 us; speedup 1.0000x reference)
//
#include <hip/hip_runtime.h>

#define B_ 8
#define N_ 1024
#define D_ 512
#define H_ 8
#define HD_ 64
#define BH_ 64   // B*H

// exact tanh via exp2-based __expf: tanh(x) = 1 - 2/(exp(2x)+1)
static __device__ __forceinline__ float fast_tanh(float x) {
    const float e = __expf(2.0f * x);
    return 1.0f - 2.0f / (e + 1.0f);
}

// ---- 64x64 tile loaders, 256 threads, pitch 68 (16B-aligned rows, conflict-light) ----
// transposed store: sm[c][r] = g[r*row_stride + c]
__device__ __forceinline__ void load_tile_T(const float* __restrict__ g, int row_stride,
                                            int tid, float sm[64][68]) {
    const int lr = tid >> 4;
    const int lc = (tid & 15) << 2;
#pragma unroll
    for (int rr = 0; rr < 64; rr += 16) {
        const float4 v = *reinterpret_cast<const float4*>(g + (lr + rr) * row_stride + lc);
        sm[lc + 0][lr + rr] = v.x;
        sm[lc + 1][lr + rr] = v.y;
        sm[lc + 2][lr + rr] = v.z;
        sm[lc + 3][lr + rr] = v.w;
    }
}

// natural store: sm[r][c] = g[r*row_stride + c]
__device__ __forceinline__ void load_tile(const float* __restrict__ g, int row_stride,
                                          int tid, float sm[64][68]) {
    const int lr = tid >> 4;
    const int lc = (tid & 15) << 2;
#pragma unroll
    for (int rr = 0; rr < 64; rr += 16) {
        const float4 v = *reinterpret_cast<const float4*>(g + (lr + rr) * row_stride + lc);
        *reinterpret_cast<float4*>(&sm[lr + rr][lc]) = v;
    }
}

// C[M=8192, 512] = X[8192,512] @ W^T[512,512] + bias ; optional permuted store to [B,H,N,HD]
__global__ __launch_bounds__(256)
void proj_kernel(const float* __restrict__ X, const float* __restrict__ W,
                 const float* __restrict__ bias, float* __restrict__ out,
                 const int permute) {
    __shared__ float As[64][68];
    __shared__ float Bs[64][68];
    const int tid = threadIdx.x;
    const int ty = tid >> 4, tx = tid & 15;
    const int row0 = blockIdx.y << 6;
    const int col0 = blockIdx.x << 6;
    float acc[4][4] = {};
    for (int k0 = 0; k0 < D_; k0 += 64) {
        load_tile_T(X + (long)row0 * D_ + k0, D_, tid, As);
        load_tile_T(W + (long)col0 * D_ + k0, D_, tid, Bs);
        __syncthreads();
#pragma unroll
        for (int kk = 0; kk < 64; ++kk) {
            const float4 a4 = *reinterpret_cast<const float4*>(&As[kk][ty << 2]);
            const float4 b4 = *reinterpret_cast<const float4*>(&Bs[kk][tx << 2]);
            const float a[4] = {a4.x, a4.y, a4.z, a4.w};
            const float b[4] = {b4.x, b4.y, b4.z, b4.w};
#pragma unroll
            for (int i = 0; i < 4; ++i)
#pragma unroll
                for (int j = 0; j < 4; ++j)
                    acc[i][j] = fmaf(a[i], b[j], acc[i][j]);
        }
        __syncthreads();
    }
#pragma unroll
    for (int i = 0; i < 4; ++i) {
        const int gi = row0 + (ty << 2) + i;
#pragma unroll
        for (int j = 0; j < 4; ++j) {
            const int gj = col0 + (tx << 2) + j;
            const float v = acc[i][j] + bias[gj];
            if (permute) {
                const int bb = gi >> 10, nn = gi & (N_ - 1);
                const int hh = gj >> 6, dd = gj & (HD_ - 1);
                out[(((long)(bb * H_ + hh) * N_) + nn) * HD_ + dd] = v;
            } else {
                out[(long)gi * D_ + gj] = v;
            }
        }
    }
}

// energy tile: QK^T/8 + feature conv + tanh's + mask, writes exp(energy) (unnormalized)
__global__ __launch_bounds__(256)
void energy_kernel(const float* __restrict__ Q, const float* __restrict__ K,
                   const float* __restrict__ speaker, const int* __restrict__ dist,
                   const int* __restrict__ topic, const int* __restrict__ red,
                   const int* __restrict__ mask,
                   const float* __restrict__ feat_w, const float* __restrict__ feat_b,
                   const float* __restrict__ comb_w, const float* __restrict__ comb_b,
                   const float* __restrict__ dist_tab, const float* __restrict__ topic_tab,
                   const float* __restrict__ red_tab,
                   float* __restrict__ P) {
    __shared__ float Qs[64][68];
    __shared__ float Ks[64][68];
    __shared__ float dtab[2047];
    const int tid = threadIdx.x;
    const int bh = blockIdx.z;
    const int b = bh >> 3, h = bh & 7;
    const int i0 = blockIdx.y << 6;
    const int j0 = blockIdx.x << 6;
    for (int t = tid; t < 2047; t += 256) dtab[t] = dist_tab[t];
    load_tile_T(Q + ((long)bh * N_ + i0) * HD_, HD_, tid, Qs);
    load_tile_T(K + ((long)bh * N_ + j0) * HD_, HD_, tid, Ks);
    __syncthreads();
    const int ty = tid >> 4, tx = tid & 15;
    float acc[4][4] = {};
#pragma unroll
    for (int kk = 0; kk < 64; ++kk) {
        const float4 a4 = *reinterpret_cast<const float4*>(&Qs[kk][ty << 2]);
        const float4 b4 = *reinterpret_cast<const float4*>(&Ks[kk][tx << 2]);
        const float a[4] = {a4.x, a4.y, a4.z, a4.w};
        const float b2[4] = {b4.x, b4.y, b4.z, b4.w};
#pragma unroll
        for (int i = 0; i < 4; ++i)
#pragma unroll
            for (int j = 0; j < 4; ++j)
                acc[i][j] = fmaf(a[i], b2[j], acc[i][j]);
    }
    const float fw0 = feat_w[h * 4 + 0], fw1 = feat_w[h * 4 + 1];
    const float fw2 = feat_w[h * 4 + 2], fw3 = feat_w[h * 4 + 3];
    const float fb = feat_b[h];
    const float cw0 = comb_w[0], cw1 = comb_w[1], cb = comb_b[0];
    const float tt1 = topic_tab[1], rt1 = red_tab[1];
    const int gj = j0 + (tx << 2);
    const int4 mv = *reinterpret_cast<const int4*>(mask + b * N_ + gj);
    const int mvv[4] = {mv.x, mv.y, mv.z, mv.w};
#pragma unroll
    for (int ii = 0; ii < 4; ++ii) {
        const int gi = i0 + (ty << 2) + ii;
        const long aoff = ((long)b * N_ + gi) * N_ + gj;
        const float4 spk = *reinterpret_cast<const float4*>(speaker + aoff);
        const int4 di = *reinterpret_cast<const int4*>(dist + aoff);
        const int4 to = *reinterpret_cast<const int4*>(topic + aoff);
        const int4 re = *reinterpret_cast<const int4*>(red + aoff);
        const float spkv[4] = {spk.x, spk.y, spk.z, spk.w};
        const int dov[4] = {di.x, di.y, di.z, di.w};
        const int tov[4] = {to.x, to.y, to.z, to.w};
        const int rev[4] = {re.x, re.y, re.z, re.w};
        float4 pv;
        float* pvp = &pv.x;
#pragma unroll
        for (int jj = 0; jj < 4; ++jj) {
            float e = acc[ii][jj] * 0.125f;
            float fco;
            if (rev[jj] == 0) {
                fco = -10.0f;
                e = -15.0f;
            } else {
                const float fd = dtab[dov[jj]];
                const float ft = tov[jj] ? tt1 : 0.0f;
                fco = fast_tanh(fw0 * fd + fw1 * spkv[jj] + fw2 * ft + fw3 * rt1 + fb);
            }
            e = fast_tanh(cw0 * e + cw1 * fco + cb);
            pvp[jj] = mvv[jj] ? __expf(e) : 0.0f;
        }
        *reinterpret_cast<float4*>(P + ((long)bh * N_ + gi) * N_ + gj) = pv;
    }
}

// in-place row softmax normalization: one block per row of 1024
__global__ __launch_bounds__(256)
void softmax_norm_kernel(float* __restrict__ P) {
    const long row = blockIdx.x;
    float* p = P + row * N_;
    const int tid = threadIdx.x;
    float4 v = *reinterpret_cast<float4*>(p + (tid << 2));
    float s = v.x + v.y + v.z + v.w;
#pragma unroll
    for (int off = 1; off < 64; off <<= 1) s += __shfl_xor(s, off, 64);
    __shared__ float wsum[4];
    if ((tid & 63) == 0) wsum[tid >> 6] = s;
    __syncthreads();
    const float inv = 1.0f / (wsum[0] + wsum[1] + wsum[2] + wsum[3]);
    v.x *= inv; v.y *= inv; v.z *= inv; v.w *= inv;
    *reinterpret_cast<float4*>(p + (tid << 2)) = v;
}

// xtmp[b, i, h*64+d] = sum_j A[bh,i,j] * V[bh,j,d]
__global__ __launch_bounds__(256)
void av_kernel(const float* __restrict__ A, const float* __restrict__ V,
               float* __restrict__ xtmp) {
    __shared__ float As[64][68];
    __shared__ float Vs[64][68];
    const int tid = threadIdx.x;
    const int bh = blockIdx.y;
    const int b = bh >> 3, h = bh & 7;
    const int i0 = blockIdx.x << 6;
    const int ty = tid >> 4, tx = tid & 15;
    float acc[4][4] = {};
    const float* Ab = A + (long)bh * N_ * N_ + (long)i0 * N_;
    const float* Vb = V + (long)bh * N_ * HD_;
    for (int j0 = 0; j0 < N_; j0 += 64) {
        load_tile_T(Ab + j0, N_, tid, As);
        load_tile(Vb + (long)j0 * HD_, HD_, tid, Vs);
        __syncthreads();
#pragma unroll
        for (int kk = 0; kk < 64; ++kk) {
            const float4 a4 = *reinterpret_cast<const float4*>(&As[kk][ty << 2]);
            const float4 b4 = *reinterpret_cast<const float4*>(&Vs[kk][tx << 2]);
            const float a[4] = {a4.x, a4.y, a4.z, a4.w};
            const float b2[4] = {b4.x, b4.y, b4.z, b4.w};
#pragma unroll
            for (int i = 0; i < 4; ++i)
#pragma unroll
                for (int j = 0; j < 4; ++j)
                    acc[i][j] = fmaf(a[i], b2[j], acc[i][j]);
        }
        __syncthreads();
    }
#pragma unroll
    for (int i = 0; i < 4; ++i) {
        const int gi = i0 + (ty << 2) + i;
#pragma unroll
        for (int j = 0; j < 4; ++j) {
            const int d = (tx << 2) + j;
            xtmp[((long)b * N_ + gi) * D_ + h * HD_ + d] = acc[i][j];
        }
    }
}

extern "C" void kernel_launch(void* const* d_in, const int* in_sizes, int n_in,
                              void* d_out, int out_size, void* d_ws, size_t ws_size,
                              hipStream_t stream) {
    const float* query   = (const float*)d_in[0];
    const float* key     = (const float*)d_in[1];
    const float* value   = (const float*)d_in[2];
    const float* speaker = (const float*)d_in[3];
    const int*   dist    = (const int*)d_in[4];
    const int*   topic   = (const int*)d_in[5];
    const int*   red     = (const int*)d_in[6];
    const int*   mask    = (const int*)d_in[7];
    const float* Wq = (const float*)d_in[8];
    const float* bq = (const float*)d_in[9];
    const float* Wk = (const float*)d_in[10];
    const float* bk = (const float*)d_in[11];
    const float* Wv = (const float*)d_in[12];
    const float* bv = (const float*)d_in[13];
    const float* Wo = (const float*)d_in[14];
    const float* bo = (const float*)d_in[15];
    const float* feat_w = (const float*)d_in[16];
    const float* feat_b = (const float*)d_in[17];
    const float* comb_w = (const float*)d_in[18];
    const float* comb_b = (const float*)d_in[19];
    const float* dist_tab  = (const float*)d_in[20];
    const float* topic_tab = (const float*)d_in[21];
    const float* red_tab   = (const float*)d_in[22];

    float* out = (float*)d_out;
    float* out_x   = out;                          // [B,N,D]
    float* out_att = out + (long)B_ * N_ * D_;     // [B,H,N,N]

    // ws layout: Q [16MB] | K [16MB] ; V lives in out_x region until the end;
    // xtmp aliases Q (dead after energy kernel). Total ws need: 32 MB.
    float* Qw   = (float*)d_ws;
    float* Kw   = Qw + (long)BH_ * N_ * HD_;
    float* Vw   = out_x;       // V parked in the x-output region (overwritten last)
    float* xtmp = Qw;          // alias: Q dead after energy_kernel

    const dim3 blk(256);
    const dim3 gproj(D_ / 64, (B_ * N_) / 64);   // (8, 128)

    hipLaunchKernelGGL(proj_kernel, gproj, blk, 0, stream, query, Wq, bq, Qw, 1);
    hipLaunchKernelGGL(proj_kernel, gproj, blk, 0, stream, key,   Wk, bk, Kw, 1);
    hipLaunchKernelGGL(proj_kernel, gproj, blk, 0, stream, value, Wv, bv, Vw, 1);

    const dim3 genergy(N_ / 64, N_ / 64, BH_);   // (16,16,64)
    hipLaunchKernelGGL(energy_kernel, genergy, blk, 0, stream,
                       Qw, Kw, speaker, dist, topic, red, mask,
                       feat_w, feat_b, comb_w, comb_b, dist_tab, topic_tab, red_tab,
                       out_att);

    hipLaunchKernelGGL(softmax_norm_kernel, dim3(BH_ * N_), blk, 0, stream, out_att);

    const dim3 gav(N_ / 64, BH_);                // (16,64)
    hipLaunchKernelGGL(av_kernel, gav, blk, 0, stream, out_att, Vw, xtmp);

    hipLaunchKernelGGL(proj_kernel, gproj, blk, 0, stream, xtmp, Wo, bo, out_x, 0);
}

// Round 2
// 999.155 us; speedup vs baseline: 3.1903x; 3.1903x over previous
//
#include <hip/hip_runtime.h>

#define B_ 8
#define N_ 1024
#define D_ 512
#define H_ 8
#define HD_ 64
#define BH_ 64

// tanh(x) = 1 - 2/(exp(2x)+1); rcp is the 1-ulp v_rcp_f32, no IEEE div sequence
static __device__ __forceinline__ float fast_tanh(float x) {
    const float e2 = __expf(2.0f * x);
    return 1.0f - 2.0f * __builtin_amdgcn_rcpf(e2 + 1.0f);
}

// ---- unified 64x64 f32 LDS tile, natural row-major, XOR chunk swizzle ----
// chunk c4 (0..15, 4 floats each) of row r stored at slot ((c4 ^ (r>>2)) & 7) | (c4 & 8)
static __device__ __forceinline__ int tile_off(int r, int c4) {
    return (r << 6) + (((((r >> 2) ^ c4) & 7) | (c4 & 8)) << 2);
}

static __device__ __forceinline__ void load_tile64(const float* __restrict__ g, int row_stride,
                                                   int tid, float* __restrict__ sm) {
    const int lr = tid >> 4;
    const int lc4 = tid & 15;
#pragma unroll
    for (int rr = 0; rr < 64; rr += 16) {
        const int r = lr + rr;
        const float4 v = *reinterpret_cast<const float4*>(g + (long)r * row_stride + (lc4 << 2));
        *reinterpret_cast<float4*>(sm + tile_off(r, lc4)) = v;
    }
}

static __device__ __forceinline__ float4 tile_frag(const float* __restrict__ sm, int r, int c4) {
    return *reinterpret_cast<const float4*>(sm + tile_off(r, c4));
}

// acc[i][j] += sum_k A[i][k]*B[j][k] over one staged chunk column
#define DOT_CHUNK(As, Bs)                                                          \
    {                                                                              \
        float4 a[4], b[4];                                                         \
        _Pragma("unroll") for (int i = 0; i < 4; ++i)                              \
            a[i] = tile_frag(As, (ty << 2) + i, c4);                               \
        _Pragma("unroll") for (int j = 0; j < 4; ++j)                              \
            b[j] = tile_frag(Bs, (tx << 2) + j, c4);                               \
        _Pragma("unroll") for (int i = 0; i < 4; ++i)                              \
            _Pragma("unroll") for (int j = 0; j < 4; ++j) {                        \
                acc[i][j] = fmaf(a[i].x, b[j].x, acc[i][j]);                       \
                acc[i][j] = fmaf(a[i].y, b[j].y, acc[i][j]);                       \
                acc[i][j] = fmaf(a[i].z, b[j].z, acc[i][j]);                       \
                acc[i][j] = fmaf(a[i].w, b[j].w, acc[i][j]);                       \
            }                                                                      \
    }

// C[8192,512] = X[8192,512] @ W^T + bias; optional permuted store to [B,H,N,HD]
__global__ __launch_bounds__(256, 4)
void proj_kernel(const float* __restrict__ X, const float* __restrict__ W,
                 const float* __restrict__ bias, float* __restrict__ out,
                 const int permute) {
    __shared__ float As[4096];
    __shared__ float Bs[4096];
    const int tid = threadIdx.x;
    const int ty = tid >> 4, tx = tid & 15;
    const int row0 = blockIdx.y << 6;
    const int col0 = blockIdx.x << 6;
    float acc[4][4] = {};
    for (int k0 = 0; k0 < D_; k0 += 64) {
        if (k0) __syncthreads();
        load_tile64(X + (long)row0 * D_ + k0, D_, tid, As);
        load_tile64(W + (long)col0 * D_ + k0, D_, tid, Bs);
        __syncthreads();
#pragma unroll
        for (int c4 = 0; c4 < 16; ++c4) DOT_CHUNK(As, Bs)
    }
#pragma unroll
    for (int i = 0; i < 4; ++i) {
        const int gi = row0 + (ty << 2) + i;
#pragma unroll
        for (int j = 0; j < 4; ++j) {
            const int gj = col0 + (tx << 2) + j;
            const float v = acc[i][j] + bias[gj];
            if (permute) {
                const int bb = gi >> 10, nn = gi & (N_ - 1);
                const int hh = gj >> 6, dd = gj & (HD_ - 1);
                out[(((long)(bb * H_ + hh) * N_) + nn) * HD_ + dd] = v;
            } else {
                out[(long)gi * D_ + gj] = v;
            }
        }
    }
}

// one block per (b, i-tile, j-tile); loops all 8 heads; writes exp(energy) unnormalized
__global__ __launch_bounds__(256, 4)
void energy_kernel(const float* __restrict__ Q, const float* __restrict__ K,
                   const float* __restrict__ speaker, const int* __restrict__ dist,
                   const int* __restrict__ topic, const int* __restrict__ red,
                   const int* __restrict__ mask,
                   const float* __restrict__ feat_w, const float* __restrict__ feat_b,
                   const float* __restrict__ comb_w, const float* __restrict__ comb_b,
                   const float* __restrict__ dist_tab, const float* __restrict__ topic_tab,
                   const float* __restrict__ red_tab,
                   float* __restrict__ P) {
    __shared__ float Qs[4096];
    __shared__ float Ks[4096];
    __shared__ float dtab[2048];
    const int tid = threadIdx.x;
    const int ty = tid >> 4, tx = tid & 15;
    const int b = blockIdx.z;
    const int i0 = blockIdx.y << 6;
    const int j0 = blockIdx.x << 6;

    for (int t = tid; t < 2047; t += 256) dtab[t] = dist_tab[t];

    // per-thread adjacency: 16 elements at rows i0+4ty+ii, cols j0+4tx..+3, loaded ONCE
    const int gj = j0 + (tx << 2);
    float spk[4][4];
    int dov[4][4];
    unsigned tbits = 0, rbits = 0;
#pragma unroll
    for (int ii = 0; ii < 4; ++ii) {
        const int gi = i0 + (ty << 2) + ii;
        const long aoff = ((long)b * N_ + gi) * N_ + gj;
        const float4 s4 = *reinterpret_cast<const float4*>(speaker + aoff);
        const int4 d4 = *reinterpret_cast<const int4*>(dist + aoff);
        const int4 t4 = *reinterpret_cast<const int4*>(topic + aoff);
        const int4 r4 = *reinterpret_cast<const int4*>(red + aoff);
        spk[ii][0] = s4.x; spk[ii][1] = s4.y; spk[ii][2] = s4.z; spk[ii][3] = s4.w;
        dov[ii][0] = d4.x; dov[ii][1] = d4.y; dov[ii][2] = d4.z; dov[ii][3] = d4.w;
        tbits |= (unsigned)(t4.x != 0) << (ii * 4 + 0);
        tbits |= (unsigned)(t4.y != 0) << (ii * 4 + 1);
        tbits |= (unsigned)(t4.z != 0) << (ii * 4 + 2);
        tbits |= (unsigned)(t4.w != 0) << (ii * 4 + 3);
        rbits |= (unsigned)(r4.x != 0) << (ii * 4 + 0);
        rbits |= (unsigned)(r4.y != 0) << (ii * 4 + 1);
        rbits |= (unsigned)(r4.z != 0) << (ii * 4 + 2);
        rbits |= (unsigned)(r4.w != 0) << (ii * 4 + 3);
    }
    const int4 m4 = *reinterpret_cast<const int4*>(mask + b * N_ + gj);
    const unsigned mbits = (unsigned)(m4.x != 0) | ((unsigned)(m4.y != 0) << 1) |
                           ((unsigned)(m4.z != 0) << 2) | ((unsigned)(m4.w != 0) << 3);

    // stage head-0 tiles together with dtab, single barrier
    load_tile64(Q + ((long)(b * H_) * N_ + i0) * HD_, HD_, tid, Qs);
    load_tile64(K + ((long)(b * H_) * N_ + j0) * HD_, HD_, tid, Ks);
    __syncthreads();

    float fd[4][4];
#pragma unroll
    for (int ii = 0; ii < 4; ++ii)
#pragma unroll
        for (int jj = 0; jj < 4; ++jj) fd[ii][jj] = dtab[dov[ii][jj]];

    const float tt1 = topic_tab[1], rt1 = red_tab[1];
    const float cw0 = comb_w[0], cw1 = comb_w[1], cb = comb_b[0];

    for (int h = 0; h < H_; ++h) {
        if (h) {
            __syncthreads();
            load_tile64(Q + ((long)(b * H_ + h) * N_ + i0) * HD_, HD_, tid, Qs);
            load_tile64(K + ((long)(b * H_ + h) * N_ + j0) * HD_, HD_, tid, Ks);
            __syncthreads();
        }
        float acc[4][4] = {};
#pragma unroll
        for (int c4 = 0; c4 < 16; ++c4) DOT_CHUNK(Qs, Ks)

        const float fw0 = feat_w[h * 4 + 0], fw1 = feat_w[h * 4 + 1];
        const float th2 = feat_w[h * 4 + 2] * tt1;
        const float fbh = feat_b[h] + feat_w[h * 4 + 3] * rt1;  // fr term always rt1 when unmasked
#pragma unroll
        for (int ii = 0; ii < 4; ++ii) {
            const int gi = i0 + (ty << 2) + ii;
            float4 pv;
            float* pvp = &pv.x;
#pragma unroll
            for (int jj = 0; jj < 4; ++jj) {
                const int e = ii * 4 + jj;
                const int alive = (rbits >> e) & 1;
                float s = fbh + (((tbits >> e) & 1) ? th2 : 0.0f);
                s = fmaf(fw0, fd[ii][jj], fmaf(fw1, spk[ii][jj], s));
                float fco = fast_tanh(s);
                float en = acc[ii][jj] * 0.125f;
                if (!alive) { fco = -10.0f; en = -15.0f; }
                const float ec = fast_tanh(fmaf(cw0, en, fmaf(cw1, fco, cb)));
                pvp[jj] = ((mbits >> jj) & 1) ? __expf(ec) : 0.0f;
            }
            *reinterpret_cast<float4*>(P + (((long)(b * H_ + h) * N_ + gi) * N_) + gj) = pv;
        }
    }
}

// in-place row softmax normalization: one block per row of 1024
__global__ __launch_bounds__(256)
void softmax_norm_kernel(float* __restrict__ P) {
    const long row = blockIdx.x;
    float* p = P + row * N_;
    const int tid = threadIdx.x;
    float4 v = *reinterpret_cast<float4*>(p + (tid << 2));
    float s = v.x + v.y + v.z + v.w;
#pragma unroll
    for (int off = 1; off < 64; off <<= 1) s += __shfl_xor(s, off, 64);
    __shared__ float wsum[4];
    if ((tid & 63) == 0) wsum[tid >> 6] = s;
    __syncthreads();
    const float inv = 1.0f / (wsum[0] + wsum[1] + wsum[2] + wsum[3]);
    v.x *= inv; v.y *= inv; v.z *= inv; v.w *= inv;
    *reinterpret_cast<float4*>(p + (tid << 2)) = v;
}

// xtmp[b, i, h*64+d] = sum_jk A[bh,i,jk] * V[bh,jk,d]
__global__ __launch_bounds__(256, 4)
void av_kernel(const float* __restrict__ A, const float* __restrict__ V,
               float* __restrict__ xtmp) {
    __shared__ float As[4096];
    __shared__ float Vs[4096];
    const int tid = threadIdx.x;
    const int ty = tid >> 4, tx = tid & 15;
    const int bh = blockIdx.y;
    const int b = bh >> 3, h = bh & 7;
    const int i0 = blockIdx.x << 6;
    const float* Ab = A + ((long)bh * N_ + i0) * N_;
    const float* Vb = V + (long)bh * N_ * HD_;
    float acc[4][4] = {};
    for (int j0 = 0; j0 < N_; j0 += 64) {
        if (j0) __syncthreads();
        load_tile64(Ab + j0, N_, tid, As);
        load_tile64(Vb + (long)j0 * HD_, HD_, tid, Vs);
        __syncthreads();
#pragma unroll
        for (int c4 = 0; c4 < 16; ++c4) {
            float4 a[4];
#pragma unroll
            for (int i = 0; i < 4; ++i) a[i] = tile_frag(As, (ty << 2) + i, c4);
#define AV_STEP(COMP, KK)                                                           \
            {                                                                       \
                const float4 v4 = tile_frag(Vs, (c4 << 2) + KK, tx);                \
                _Pragma("unroll") for (int i = 0; i < 4; ++i) {                     \
                    acc[i][0] = fmaf(a[i].COMP, v4.x, acc[i][0]);                   \
                    acc[i][1] = fmaf(a[i].COMP, v4.y, acc[i][1]);                   \
                    acc[i][2] = fmaf(a[i].COMP, v4.z, acc[i][2]);                   \
                    acc[i][3] = fmaf(a[i].COMP, v4.w, acc[i][3]);                   \
                }                                                                   \
            }
            AV_STEP(x, 0)
            AV_STEP(y, 1)
            AV_STEP(z, 2)
            AV_STEP(w, 3)
#undef AV_STEP
        }
    }
#pragma unroll
    for (int i = 0; i < 4; ++i) {
        const int gi = i0 + (ty << 2) + i;
#pragma unroll
        for (int j = 0; j < 4; ++j) {
            const int d = (tx << 2) + j;
            xtmp[((long)b * N_ + gi) * D_ + h * HD_ + d] = acc[i][j];
        }
    }
}

extern "C" void kernel_launch(void* const* d_in, const int* in_sizes, int n_in,
                              void* d_out, int out_size, void* d_ws, size_t ws_size,
                              hipStream_t stream) {
    const float* query   = (const float*)d_in[0];
    const float* key     = (const float*)d_in[1];
    const float* value   = (const float*)d_in[2];
    const float* speaker = (const float*)d_in[3];
    const int*   dist    = (const int*)d_in[4];
    const int*   topic   = (const int*)d_in[5];
    const int*   red     = (const int*)d_in[6];
    const int*   mask    = (const int*)d_in[7];
    const float* Wq = (const float*)d_in[8];
    const float* bq = (const float*)d_in[9];
    const float* Wk = (const float*)d_in[10];
    const float* bk = (const float*)d_in[11];
    const float* Wv = (const float*)d_in[12];
    const float* bv = (const float*)d_in[13];
    const float* Wo = (const float*)d_in[14];
    const float* bo = (const float*)d_in[15];
    const float* feat_w = (const float*)d_in[16];
    const float* feat_b = (const float*)d_in[17];
    const float* comb_w = (const float*)d_in[18];
    const float* comb_b = (const float*)d_in[19];
    const float* dist_tab  = (const float*)d_in[20];
    const float* topic_tab = (const float*)d_in[21];
    const float* red_tab   = (const float*)d_in[22];

    float* out = (float*)d_out;
    float* out_x   = out;                          // [B,N,D]
    float* out_att = out + (long)B_ * N_ * D_;     // [B,H,N,N]

    // ws: Q [16MB] | K [16MB]; V parked in out_x region; xtmp aliases Q (dead after energy)
    float* Qw   = (float*)d_ws;
    float* Kw   = Qw + (long)BH_ * N_ * HD_;
    float* Vw   = out_x;
    float* xtmp = Qw;

    const dim3 blk(256);
    const dim3 gproj(D_ / 64, (B_ * N_) / 64);   // (8, 128)

    hipLaunchKernelGGL(proj_kernel, gproj, blk, 0, stream, query, Wq, bq, Qw, 1);
    hipLaunchKernelGGL(proj_kernel, gproj, blk, 0, stream, key,   Wk, bk, Kw, 1);
    hipLaunchKernelGGL(proj_kernel, gproj, blk, 0, stream, value, Wv, bv, Vw, 1);

    const dim3 genergy(N_ / 64, N_ / 64, B_);    // (16,16,8)
    hipLaunchKernelGGL(energy_kernel, genergy, blk, 0, stream,
                       Qw, Kw, speaker, dist, topic, red, mask,
                       feat_w, feat_b, comb_w, comb_b, dist_tab, topic_tab, red_tab,
                       out_att);

    hipLaunchKernelGGL(softmax_norm_kernel, dim3(BH_ * N_), blk, 0, stream, out_att);

    const dim3 gav(N_ / 64, BH_);                // (16,64)
    hipLaunchKernelGGL(av_kernel, gav, blk, 0, stream, out_att, Vw, xtmp);

    hipLaunchKernelGGL(proj_kernel, gproj, blk, 0, stream, xtmp, Wo, bo, out_x, 0);
}

// Round 4
// 741.658 us; speedup vs baseline: 4.2979x; 1.3472x over previous
//
#include <hip/hip_runtime.h>

#define B_ 8
#define N_ 1024
#define D_ 512
#define H_ 8
#define HD_ 64
#define BH_ 64

typedef unsigned short ushort_t;
using s8bf  = __attribute__((ext_vector_type(8))) short;   // 8 bf16 (4 VGPR)
using f4acc = __attribute__((ext_vector_type(4))) float;   // MFMA C/D

union FragU { uint4 u; s8bf s; };

static __device__ __forceinline__ float fast_tanh(float x) {
    const float e2 = __expf(2.0f * x);
    return 1.0f - 2.0f * __builtin_amdgcn_rcpf(e2 + 1.0f);
}

// f32 -> bf16 round-to-nearest-even
static __device__ __forceinline__ unsigned short f2bf(float x) {
    const unsigned u = __float_as_uint(x);
    return (unsigned short)((u + 0x7fffu + ((u >> 16) & 1u)) >> 16);
}

static __device__ __forceinline__ uint4 pack8(float4 a, float4 b) {
    uint4 r;
    r.x = (unsigned)f2bf(a.x) | ((unsigned)f2bf(a.y) << 16);
    r.y = (unsigned)f2bf(a.z) | ((unsigned)f2bf(a.w) << 16);
    r.z = (unsigned)f2bf(b.x) | ((unsigned)f2bf(b.y) << 16);
    r.w = (unsigned)f2bf(b.z) | ((unsigned)f2bf(b.w) << 16);
    return r;
}

// ---- swizzled bf16 LDS tiles: row = 64 bf16 = 128 B; 16B chunk c at byte
// r*128 + ((c ^ (r&7))<<4). 8B chunk c8 at r*128 + ((c8 ^ ((r&7)<<1))<<3). ----

template <int ROWS>
static __device__ __forceinline__ void stage_f32(const float* __restrict__ g, long stride,
                                                 char* __restrict__ lds, int tid) {
#pragma unroll
    for (int m = 0; m < ROWS / 32; ++m) {
        const int u = tid + (m << 8);
        const int r = u >> 3, c = u & 7;
        const float* s = g + (long)r * stride + (c << 3);
        const float4 a = *(const float4*)s;
        const float4 b = *(const float4*)(s + 4);
        *(uint4*)(lds + (r << 7) + ((c ^ (r & 7)) << 4)) = pack8(a, b);
    }
}

template <int ROWS>
static __device__ __forceinline__ void stage_bf16(const ushort_t* __restrict__ g, long stride,
                                                  char* __restrict__ lds, int tid) {
#pragma unroll
    for (int m = 0; m < ROWS / 32; ++m) {
        const int u = tid + (m << 8);
        const int r = u >> 3, c = u & 7;
        const uint4 v = *(const uint4*)(g + (long)r * stride + (c << 3));
        *(uint4*)(lds + (r << 7) + ((c ^ (r & 7)) << 4)) = v;
    }
}

// A/B fragment for mfma_f32_16x16x32_bf16: regs 0-3 = k=(kh*32)+lanehi*4+e,
// regs 4-7 = k=(kh*32)+16+lanehi*4+e   (two K=16 halves)
static __device__ __forceinline__ s8bf frag_ld(const char* __restrict__ lds, int r, int kh,
                                               int lanehi) {
    const int swz = (r & 7) << 1;
    const char* row = lds + (r << 7);
    FragU f;
    *(uint2*)&f.u.x = *(const uint2*)(row + ((((kh << 3) + lanehi) ^ swz) << 3));
    *(uint2*)&f.u.z = *(const uint2*)(row + ((((kh << 3) + 4 + lanehi) ^ swz) << 3));
    return f.s;
}

static __device__ __forceinline__ f4acc mfma16(s8bf a, s8bf b, f4acc c) {
    return __builtin_amdgcn_mfma_f32_16x16x32_bf16(a, b, c, 0, 0, 0);
}

// ---------- projection: C[8192,512] = X @ W^T + bias ----------
// MODE 0: f32 out [m][512]. MODE 1: bf16 out [b,h,n,hd]. MODE 2: bf16 out [bh][hd][n] (V^T)
template <int MODE, int ABF16>
__global__ __launch_bounds__(256, 3)
void proj_mfma(const void* __restrict__ Xv, const float* __restrict__ W,
               const float* __restrict__ bias, void* __restrict__ out) {
    __shared__ char As[128 * 128];
    __shared__ char Bs[64 * 128];
    const int tid = threadIdx.x;
    const int lane = tid & 63, wid = tid >> 6;
    const int lanelo = lane & 15, lanehi = lane >> 4;
    const int row0 = blockIdx.y << 7;
    const int col0 = blockIdx.x << 6;
    f4acc acc[2][4] = {};
    for (int k0 = 0; k0 < D_; k0 += 64) {
        if (k0) __syncthreads();
        if (ABF16)
            stage_bf16<128>((const ushort_t*)Xv + (long)row0 * D_ + k0, D_, As, tid);
        else
            stage_f32<128>((const float*)Xv + (long)row0 * D_ + k0, D_, As, tid);
        stage_f32<64>(W + (long)col0 * D_ + k0, D_, Bs, tid);
        __syncthreads();
#pragma unroll
        for (int kh = 0; kh < 2; ++kh) {
            s8bf bfr[4], afr[2];
#pragma unroll
            for (int nt = 0; nt < 4; ++nt) bfr[nt] = frag_ld(Bs, (nt << 4) + lanelo, kh, lanehi);
#pragma unroll
            for (int mt = 0; mt < 2; ++mt)
                afr[mt] = frag_ld(As, (wid << 5) + (mt << 4) + lanelo, kh, lanehi);
#pragma unroll
            for (int mt = 0; mt < 2; ++mt)
#pragma unroll
                for (int nt = 0; nt < 4; ++nt) acc[mt][nt] = mfma16(afr[mt], bfr[nt], acc[mt][nt]);
        }
    }
#pragma unroll
    for (int mt = 0; mt < 2; ++mt)
#pragma unroll
        for (int nt = 0; nt < 4; ++nt) {
            const int gj = col0 + (nt << 4) + lanelo;
            const float bz = bias[gj];
            const int gi0 = row0 + (wid << 5) + (mt << 4) + (lanehi << 2);
            if (MODE == 2) {
                const int bb = gi0 >> 10, nn = gi0 & (N_ - 1);
                const int hh = gj >> 6, dd = gj & (HD_ - 1);
                ushort4 v;
                v.x = f2bf(acc[mt][nt][0] + bz);
                v.y = f2bf(acc[mt][nt][1] + bz);
                v.z = f2bf(acc[mt][nt][2] + bz);
                v.w = f2bf(acc[mt][nt][3] + bz);
                *(ushort4*)((ushort_t*)out + (((long)(bb * H_ + hh) * HD_ + dd) << 10) + nn) = v;
            } else {
#pragma unroll
                for (int e = 0; e < 4; ++e) {
                    const int gi = gi0 + e;
                    const float v = acc[mt][nt][e] + bz;
                    if (MODE == 0) {
                        ((float*)out)[(long)gi * D_ + gj] = v;
                    } else {
                        const int bb = gi >> 10, nn = gi & (N_ - 1);
                        const int hh = gj >> 6, dd = gj & (HD_ - 1);
                        ((ushort_t*)out)[(((long)(bb * H_ + hh) * N_) + nn) * HD_ + dd] = f2bf(v);
                    }
                }
            }
        }
}

// ---------- energy: P = exp(tanh(comb(QK^T/8, features))), row sums via atomics ----------
__global__ __launch_bounds__(256, 3)
void energy_mfma(const ushort_t* __restrict__ Q, const ushort_t* __restrict__ K,
                 const float* __restrict__ speaker, const int* __restrict__ dist,
                 const int* __restrict__ topic, const int* __restrict__ red,
                 const int* __restrict__ maskp,
                 const float* __restrict__ feat_w, const float* __restrict__ feat_b,
                 const float* __restrict__ comb_w, const float* __restrict__ comb_b,
                 const float* __restrict__ dist_tab, const float* __restrict__ topic_tab,
                 const float* __restrict__ red_tab,
                 float* __restrict__ P, float* __restrict__ rowsum) {
    __shared__ char Qs[8192];
    __shared__ char Ks[8192];
    __shared__ float dtab[2048];
    const int tid = threadIdx.x;
    const int lane = tid & 63, wid = tid >> 6;
    const int lanelo = lane & 15, lanehi = lane >> 4;
    const int b = blockIdx.z;
    const int i0 = blockIdx.y << 6;
    const int j0 = blockIdx.x << 6;

    for (int t = tid; t < 2047; t += 256) dtab[t] = dist_tab[t];

    // lane owns row gi, cols j = j0 + t*16 + lanehi*4 + e  (t=0..3, e=0..3)
    const int gi = i0 + (wid << 4) + lanelo;
    const long arow = ((long)b * N_ + gi) * N_ + j0;
    float4 sp[4];
    int4 dd4[4];
    unsigned tb = 0, rb = 0, mb = 0;
#pragma unroll
    for (int t = 0; t < 4; ++t) {
        const int jc = (t << 4) + (lanehi << 2);
        sp[t] = *(const float4*)(speaker + arow + jc);
        dd4[t] = *(const int4*)(dist + arow + jc);
        const int4 t4 = *(const int4*)(topic + arow + jc);
        const int4 r4 = *(const int4*)(red + arow + jc);
        const int4 m4 = *(const int4*)(maskp + b * N_ + j0 + jc);
        const int sh = t << 2;
        tb |= ((unsigned)(t4.x != 0) | ((unsigned)(t4.y != 0) << 1) |
               ((unsigned)(t4.z != 0) << 2) | ((unsigned)(t4.w != 0) << 3)) << sh;
        rb |= ((unsigned)(r4.x != 0) | ((unsigned)(r4.y != 0) << 1) |
               ((unsigned)(r4.z != 0) << 2) | ((unsigned)(r4.w != 0) << 3)) << sh;
        mb |= ((unsigned)(m4.x != 0) | ((unsigned)(m4.y != 0) << 1) |
               ((unsigned)(m4.z != 0) << 2) | ((unsigned)(m4.w != 0) << 3)) << sh;
    }
    __syncthreads();  // dtab ready
    float4 fd[4];
#pragma unroll
    for (int t = 0; t < 4; ++t) {
        fd[t].x = dtab[dd4[t].x]; fd[t].y = dtab[dd4[t].y];
        fd[t].z = dtab[dd4[t].z]; fd[t].w = dtab[dd4[t].w];
    }

    const float tt1 = topic_tab[1], rt1 = red_tab[1];
    const float cw0 = comb_w[0], cw1 = comb_w[1], cb = comb_b[0];

    for (int h = 0; h < H_; ++h) {
        __syncthreads();
        stage_bf16<64>(Q + ((long)(b * H_ + h) * N_ + i0) * HD_, HD_, Qs, tid);
        stage_bf16<64>(K + ((long)(b * H_ + h) * N_ + j0) * HD_, HD_, Ks, tid);
        __syncthreads();
        s8bf bq0 = frag_ld(Qs, (wid << 4) + lanelo, 0, lanehi);
        s8bf bq1 = frag_ld(Qs, (wid << 4) + lanelo, 1, lanehi);
        const float fw0 = feat_w[h * 4 + 0], fw1 = feat_w[h * 4 + 1];
        const float th2 = feat_w[h * 4 + 2] * tt1;
        const float fbh = feat_b[h] + feat_w[h * 4 + 3] * rt1;
        float rsum = 0.0f;
        float* Pr = P + (((long)(b * H_ + h) * N_ + gi) * N_) + j0 + (lanehi << 2);
#pragma unroll
        for (int t = 0; t < 4; ++t) {
            f4acc acc = {};
            acc = mfma16(frag_ld(Ks, (t << 4) + lanelo, 0, lanehi), bq0, acc);
            acc = mfma16(frag_ld(Ks, (t << 4) + lanelo, 1, lanehi), bq1, acc);
            float4 pv;
            const float* spt = &sp[t].x;
            const float* fdt = &fd[t].x;
#pragma unroll
            for (int e = 0; e < 4; ++e) {
                const int bit = (t << 2) + e;
                float s = fbh + (((tb >> bit) & 1) ? th2 : 0.0f);
                s = fmaf(fw0, fdt[e], fmaf(fw1, spt[e], s));
                float fco = fast_tanh(s);
                float en = acc[e] * 0.125f;
                if (!((rb >> bit) & 1)) { fco = -10.0f; en = -15.0f; }
                const float ec = fast_tanh(fmaf(cw0, en, fmaf(cw1, fco, cb)));
                const float p = ((mb >> bit) & 1) ? __expf(ec) : 0.0f;
                (&pv.x)[e] = p;
                rsum += p;
            }
            *(float4*)(Pr + (t << 4)) = pv;
        }
        rsum += __shfl_xor(rsum, 16, 64);
        rsum += __shfl_xor(rsum, 32, 64);
        if (lane < 16) atomicAdd(rowsum + ((long)(b * H_ + h) * N_) + gi, rsum);
    }
}

// ---------- AV: normalize P in place + x = (P @ V) * invs ----------
__global__ __launch_bounds__(256, 3)
void av_mfma(float* P, const ushort_t* __restrict__ Vt, const float* __restrict__ rowsum,
             ushort_t* __restrict__ xout) {
    __shared__ char Ps[8192];
    __shared__ char Vs[8192];
    __shared__ float invs[64];
    const int tid = threadIdx.x;
    const int lane = tid & 63, wid = tid >> 6;
    const int lanelo = lane & 15, lanehi = lane >> 4;
    const int bh = blockIdx.y;
    const int b = bh >> 3, h = bh & 7;
    const int i0 = blockIdx.x << 6;
    if (tid < 64) invs[tid] = 1.0f / rowsum[(long)bh * N_ + i0 + tid];
    f4acc acc[4] = {};
    float* Pb = P + ((long)bh * N_ + i0) * N_;
    const ushort_t* Vb = Vt + (((long)bh * HD_) << 10);
    for (int j0 = 0; j0 < N_; j0 += 64) {
        __syncthreads();
        // stage P tile (f32 -> bf16) + fused normalize write-back
#pragma unroll
        for (int m = 0; m < 2; ++m) {
            const int u = tid + (m << 8);
            const int r = u >> 3, c = u & 7;
            float* s = Pb + (long)r * N_ + j0 + (c << 3);
            float4 a = *(float4*)s;
            float4 bb = *(float4*)(s + 4);
            *(uint4*)(Ps + (r << 7) + ((c ^ (r & 7)) << 4)) = pack8(a, bb);
            const float iv = invs[r];
            a.x *= iv; a.y *= iv; a.z *= iv; a.w *= iv;
            bb.x *= iv; bb.y *= iv; bb.z *= iv; bb.w *= iv;
            *(float4*)s = a;
            *(float4*)(s + 4) = bb;
        }
        stage_bf16<64>(Vb + j0, N_, Vs, tid);
        __syncthreads();
#pragma unroll
        for (int kh = 0; kh < 2; ++kh) {
            const s8bf a = frag_ld(Ps, (wid << 4) + lanelo, kh, lanehi);
#pragma unroll
            for (int nt = 0; nt < 4; ++nt)
                acc[nt] = mfma16(a, frag_ld(Vs, (nt << 4) + lanelo, kh, lanehi), acc[nt]);
        }
    }
    const long xbase = ((long)b * N_) * D_ + (long)h * HD_;
#pragma unroll
    for (int nt = 0; nt < 4; ++nt) {
        const int d = (nt << 4) + lanelo;
#pragma unroll
        for (int e = 0; e < 4; ++e) {
            const int il = (wid << 4) + (lanehi << 2) + e;
            const float v = acc[nt][e] * invs[il];
            xout[xbase + (long)(i0 + il) * D_ + d] = f2bf(v);
        }
    }
}

extern "C" void kernel_launch(void* const* d_in, const int* in_sizes, int n_in,
                              void* d_out, int out_size, void* d_ws, size_t ws_size,
                              hipStream_t stream) {
    const float* query   = (const float*)d_in[0];
    const float* key     = (const float*)d_in[1];
    const float* value   = (const float*)d_in[2];
    const float* speaker = (const float*)d_in[3];
    const int*   dist    = (const int*)d_in[4];
    const int*   topic   = (const int*)d_in[5];
    const int*   red     = (const int*)d_in[6];
    const int*   maskp   = (const int*)d_in[7];
    const float* Wq = (const float*)d_in[8];
    const float* bq = (const float*)d_in[9];
    const float* Wk = (const float*)d_in[10];
    const float* bk = (const float*)d_in[11];
    const float* Wv = (const float*)d_in[12];
    const float* bv = (const float*)d_in[13];
    const float* Wo = (const float*)d_in[14];
    const float* bo = (const float*)d_in[15];
    const float* feat_w = (const float*)d_in[16];
    const float* feat_b = (const float*)d_in[17];
    const float* comb_w = (const float*)d_in[18];
    const float* comb_b = (const float*)d_in[19];
    const float* dist_tab  = (const float*)d_in[20];
    const float* topic_tab = (const float*)d_in[21];
    const float* red_tab   = (const float*)d_in[22];

    float* out = (float*)d_out;
    float* out_x   = out;                       // [B,N,D] f32
    float* out_att = out + (long)B_ * N_ * D_;  // [B,H,N,N] f32

    // ws: Qw bf16 8MB | Kw bf16 8MB | Vt bf16 8MB | rowsum f32 256KB ; xtmp aliases Qw
    ushort_t* Qw = (ushort_t*)d_ws;
    ushort_t* Kw = Qw + (long)BH_ * N_ * HD_;
    ushort_t* Vt = Kw + (long)BH_ * N_ * HD_;
    float* rowsum = (float*)(Vt + (long)BH_ * N_ * HD_);
    ushort_t* xtmp = Qw;

    (void)hipMemsetAsync(rowsum, 0, (size_t)BH_ * N_ * sizeof(float), stream);

    const dim3 blk(256);
    const dim3 gproj(D_ / 64, (B_ * N_) / 128);  // (8, 64)

    hipLaunchKernelGGL((proj_mfma<1, 0>), gproj, blk, 0, stream, query, Wq, bq, Qw);
    hipLaunchKernelGGL((proj_mfma<1, 0>), gproj, blk, 0, stream, key,   Wk, bk, Kw);
    hipLaunchKernelGGL((proj_mfma<2, 0>), gproj, blk, 0, stream, value, Wv, bv, Vt);

    const dim3 genergy(N_ / 64, N_ / 64, B_);    // (16,16,8)
    hipLaunchKernelGGL(energy_mfma, genergy, blk, 0, stream,
                       Qw, Kw, speaker, dist, topic, red, maskp,
                       feat_w, feat_b, comb_w, comb_b, dist_tab, topic_tab, red_tab,
                       out_att, rowsum);

    const dim3 gav(N_ / 64, BH_);                // (16,64)
    hipLaunchKernelGGL(av_mfma, gav, blk, 0, stream, out_att, Vt, rowsum, xtmp);

    hipLaunchKernelGGL((proj_mfma<0, 1>), gproj, blk, 0, stream, xtmp, Wo, bo, out_x);
}